// Round 8
// baseline (712.037 us; speedup 1.0000x reference)
//
#include <hip/hip_runtime.h>
#include <hip/hip_bf16.h>
#include <math.h>

constexpr int BATCH = 256;
constexpr int SEQ   = 128;
constexpr int FEAT  = 512;
constexpr int HID   = 512;
constexpr int G3    = 1536;

typedef __bf16 bf16x8 __attribute__((ext_vector_type(8)));
typedef float  f32x4  __attribute__((ext_vector_type(4)));
typedef int    i32x4v __attribute__((ext_vector_type(4)));

// ---------------------------------------------------------------------------
// fp32 -> bf16 convert (vectorized, 8/thread)
// ---------------------------------------------------------------------------
__global__ __launch_bounds__(256) void convert_bf16(
    const float* __restrict__ in, __hip_bfloat16* __restrict__ out, int n)
{
  int i = (blockIdx.x * 256 + threadIdx.x) * 8;
  if (i >= n) return;
  float4 v0 = *(const float4*)&in[i];
  float4 v1 = *(const float4*)&in[i + 4];
  __hip_bfloat16 o[8];
  o[0] = (__hip_bfloat16)v0.x; o[1] = (__hip_bfloat16)v0.y;
  o[2] = (__hip_bfloat16)v0.z; o[3] = (__hip_bfloat16)v0.w;
  o[4] = (__hip_bfloat16)v1.x; o[5] = (__hip_bfloat16)v1.y;
  o[6] = (__hip_bfloat16)v1.z; o[7] = (__hip_bfloat16)v1.w;
  *(int4*)&out[i] = *(int4*)o;
}

// ---------------------------------------------------------------------------
// transpose + convert: in[512][1536] f32 -> outT[1536][512] bf16
// ---------------------------------------------------------------------------
__global__ __launch_bounds__(256) void transpose_convert(
    const float* __restrict__ in, __hip_bfloat16* __restrict__ outT)
{
  __shared__ float tile[32][33];
  const int c0 = blockIdx.x * 32;
  const int r0 = blockIdx.y * 32;
  const int tid = threadIdx.x;
  {
    int row = tid >> 3, c4 = tid & 7;
    float4 v = *(const float4*)&in[(size_t)(r0 + row) * G3 + c0 + c4 * 4];
    tile[row][c4 * 4 + 0] = v.x;
    tile[row][c4 * 4 + 1] = v.y;
    tile[row][c4 * 4 + 2] = v.z;
    tile[row][c4 * 4 + 3] = v.w;
  }
  __syncthreads();
  {
    int rowT = tid >> 3, c4 = tid & 7;
    __hip_bfloat16 o[4];
#pragma unroll
    for (int e = 0; e < 4; ++e)
      o[e] = (__hip_bfloat16)tile[c4 * 4 + e][rowT];
    *(int2*)&outT[(size_t)(c0 + rowT) * FEAT + r0 + c4 * 4] = *(int2*)o;
  }
}

// ---------------------------------------------------------------------------
// proj: 128x128 tile, BK=64, 2-phase double-buffered global_load_lds with
// XOR source/read swizzle (0 bank conflicts, one barrier per K-tile).
// ---------------------------------------------------------------------------
__global__ __launch_bounds__(256) void proj_mfma(
    const __hip_bfloat16* __restrict__ xb, const __hip_bfloat16* __restrict__ WkT,
    const float* __restrict__ bias, __hip_bfloat16* __restrict__ xp)
{
  __shared__ __align__(16) __hip_bfloat16 As[2][128 * 64];
  __shared__ __align__(16) __hip_bfloat16 Bs[2][128 * 64];

  const int tid = threadIdx.x;
  const int wave = tid >> 6, l = tid & 63;
  const int wm = wave >> 1, wn = wave & 1;
  const int m0 = blockIdx.y * 128;
  const int n0 = blockIdx.x * 128;
  const int lr = l & 15, lh = l >> 4;
  const int swz = lr & 7;

  const int srow = l >> 3;
  const int schk = l & 7;
  const int wrow = wave * 32;

  f32x4 acc[4][4] = {};

#define PROJ_STAGE(K0, SEL)                                                      \
  {                                                                              \
    _Pragma("unroll")                                                            \
    for (int i = 0; i < 4; ++i) {                                                \
      int r = wrow + i * 8 + srow;                                               \
      const __hip_bfloat16* srcA =                                               \
          &xb[(size_t)(m0 + r) * FEAT + (K0) + ((schk ^ srow) * 8)];             \
      __builtin_amdgcn_global_load_lds(                                          \
          (const __attribute__((address_space(1))) void*)srcA,                   \
          (__attribute__((address_space(3))) void*)&As[SEL][(wrow + i * 8) * 64],\
          16, 0, 0);                                                             \
    }                                                                            \
    _Pragma("unroll")                                                            \
    for (int i = 0; i < 4; ++i) {                                                \
      int r = wrow + i * 8 + srow;                                               \
      const __hip_bfloat16* srcB =                                               \
          &WkT[(size_t)(n0 + r) * FEAT + (K0) + ((schk ^ srow) * 8)];            \
      __builtin_amdgcn_global_load_lds(                                          \
          (const __attribute__((address_space(1))) void*)srcB,                   \
          (__attribute__((address_space(3))) void*)&Bs[SEL][(wrow + i * 8) * 64],\
          16, 0, 0);                                                             \
    }                                                                            \
  }

  PROJ_STAGE(0, 0);
  __syncthreads();

  int cur = 0;
  for (int kt = 0; kt < 8; ++kt) {
    if (kt < 7) PROJ_STAGE((kt + 1) * 64, cur ^ 1);

#pragma unroll
    for (int ks = 0; ks < 2; ++ks) {
      bf16x8 a[4], b[4];
#pragma unroll
      for (int i = 0; i < 4; ++i) {
        int row = wm * 64 + i * 16 + lr;
        a[i] = *(const bf16x8*)&As[cur][row * 64 + (((ks * 4 + lh) ^ swz) * 8)];
      }
#pragma unroll
      for (int j = 0; j < 4; ++j) {
        int row = wn * 64 + j * 16 + lr;
        b[j] = *(const bf16x8*)&Bs[cur][row * 64 + (((ks * 4 + lh) ^ swz) * 8)];
      }
#pragma unroll
      for (int i = 0; i < 4; ++i)
#pragma unroll
        for (int j = 0; j < 4; ++j)
          acc[i][j] = __builtin_amdgcn_mfma_f32_16x16x32_bf16(a[i], b[j], acc[i][j], 0, 0, 0);
    }
    __syncthreads();
    cur ^= 1;
  }

  float bv[4];
#pragma unroll
  for (int j = 0; j < 4; ++j)
    bv[j] = bias[n0 + wn * 64 + j * 16 + lr];
#pragma unroll
  for (int i = 0; i < 4; ++i)
#pragma unroll
    for (int j = 0; j < 4; ++j) {
      int n = n0 + wn * 64 + j * 16 + lr;
#pragma unroll
      for (int r = 0; r < 4; ++r) {
        int m = m0 + wm * 64 + i * 16 + lh * 4 + r;
        xp[(size_t)m * G3 + n] = (__hip_bfloat16)(acc[i][j][r] + bv[j]);
      }
    }
#undef PROJ_STAGE
}

// ---------------------------------------------------------------------------
// Persistent GRU recurrence, v5: short publish path.
//   - W register-stationary (pinned; lives in unified VGPR/AGPR file).
//   - Loop top: xp(t) + h(t) loads issued together, ONE vmcnt(0).
//   - Publish: per-wave vmcnt(0) -> LDS monotonic counter; 4th wave stores
//     the block flag. No pre-flag __syncthreads.
//   - Poll: leader, 4x dwordx4 on the group's 64-B flag line, busy-spin.
// Grid 256: blockIdx.x = jt*16 + bt.
// ---------------------------------------------------------------------------
__global__ __launch_bounds__(256, 1) void gru_persist(
    __hip_bfloat16* __restrict__ hbA, __hip_bfloat16* __restrict__ hbB,
    float* __restrict__ h32,
    const __hip_bfloat16* __restrict__ xp,
    const __hip_bfloat16* __restrict__ WrT,
    const float* __restrict__ br,
    int* slots)                               // [16][16] ints, 64 B per group
{
  __shared__ float red[2 * 16 * 100];
  __shared__ int wdone;

  const int tid = threadIdx.x;
  const int bt = blockIdx.x & 15;
  const int jt = blockIdx.x >> 4;
  const int wave = tid >> 6, l = tid & 63;
  const int kh = wave & 1, ch = wave >> 1;
  const int lr = l & 15, lh = l >> 4;

  // ---- one-time: W fragments -> registers (24 x 16B per lane), pinned ----
  bf16x8 wfrag[8][3];
#pragma unroll
  for (int f = 0; f < 3; ++f) {
    int r = ch * 48 + f * 16 + lr;
    int n = (r >> 5) * HID + jt * 32 + (r & 31);
    const __hip_bfloat16* wp = &WrT[(size_t)n * HID + kh * 256 + lh * 8];
#pragma unroll
    for (int ks = 0; ks < 8; ++ks)
      wfrag[ks][f] = *(const bf16x8*)&wp[ks * 32];
  }
  asm volatile(""
      : "+v"(wfrag[0][0]), "+v"(wfrag[0][1]), "+v"(wfrag[0][2]),
        "+v"(wfrag[1][0]), "+v"(wfrag[1][1]), "+v"(wfrag[1][2]),
        "+v"(wfrag[2][0]), "+v"(wfrag[2][1]), "+v"(wfrag[2][2]),
        "+v"(wfrag[3][0]), "+v"(wfrag[3][1]), "+v"(wfrag[3][2]),
        "+v"(wfrag[4][0]), "+v"(wfrag[4][1]), "+v"(wfrag[4][2]),
        "+v"(wfrag[5][0]), "+v"(wfrag[5][1]), "+v"(wfrag[5][2]),
        "+v"(wfrag[6][0]), "+v"(wfrag[6][1]), "+v"(wfrag[6][2]),
        "+v"(wfrag[7][0]), "+v"(wfrag[7][1]), "+v"(wfrag[7][2]));

  // ---- per-thread epilogue ownership ----
  const int m = tid >> 4, q4 = tid & 15;
  const int b = bt * 16 + m;
  const int jl0 = q4 * 2;
  const int jg0 = jt * 32 + jl0;
  float brz[2], brr[2], brh[2], hreg[2];
#pragma unroll
  for (int p = 0; p < 2; ++p) {
    brz[p] = br[jg0 + p];
    brr[p] = br[HID + jg0 + p];
    brh[p] = br[2 * HID + jg0 + p];
    hreg[p] = 0.f;
  }

  if (tid == 0) wdone = 0;   // first read is after iter-0's red __syncthreads

  // per-lane h-fragment base (bytes)
  const char* baseA = (const char*)hbA + ((size_t)(bt * 16 + lr) * HID + kh * 256 + lh * 8) * 2;
  const char* baseB = (const char*)hbB + ((size_t)(bt * 16 + lr) * HID + kh * 256 + lh * 8) * 2;

  for (int t = 0; t < SEQ; ++t) {
    const char* hp = (t & 1) ? baseB : baseA;
    __hip_bfloat16* nxt = (t & 1) ? hbA : hbB;

    // ---- xp(t) loads (plain, cached) — issued before the h batch ----
    const __hip_bfloat16* xq = &xp[((size_t)b * SEQ + t) * G3 + jg0];
    unsigned int uz = *(const unsigned int*)&xq[0];
    unsigned int ur_ = *(const unsigned int*)&xq[HID];
    unsigned int uh_ = *(const unsigned int*)&xq[2 * HID];

    // ---- h fragments: 8 batched coherent 16B loads, ONE waitcnt ----
    i32x4v r0, r1, r2, r3, r4, r5, r6, r7;
    asm volatile(
        "global_load_dwordx4 %0, %8, off sc0 sc1\n\t"
        "global_load_dwordx4 %1, %8, off offset:64 sc0 sc1\n\t"
        "global_load_dwordx4 %2, %8, off offset:128 sc0 sc1\n\t"
        "global_load_dwordx4 %3, %8, off offset:192 sc0 sc1\n\t"
        "global_load_dwordx4 %4, %8, off offset:256 sc0 sc1\n\t"
        "global_load_dwordx4 %5, %8, off offset:320 sc0 sc1\n\t"
        "global_load_dwordx4 %6, %8, off offset:384 sc0 sc1\n\t"
        "global_load_dwordx4 %7, %8, off offset:448 sc0 sc1\n\t"
        "s_waitcnt vmcnt(0)"
        : "=&v"(r0), "=&v"(r1), "=&v"(r2), "=&v"(r3),
          "=&v"(r4), "=&v"(r5), "=&v"(r6), "=&v"(r7)
        : "v"(hp)
        : "memory");
    union { i32x4v q; bf16x8 v; } u0, u1, u2, u3, u4, u5, u6, u7;
    u0.q = r0; u1.q = r1; u2.q = r2; u3.q = r3;
    u4.q = r4; u5.q = r5; u6.q = r6; u7.q = r7;
    bf16x8 afrag[8] = {u0.v, u1.v, u2.v, u3.v, u4.v, u5.v, u6.v, u7.v};

    // ---- MFMA: pure register operands ----
    f32x4 acc[3] = {};
#pragma unroll
    for (int ks = 0; ks < 8; ++ks)
#pragma unroll
      for (int f = 0; f < 3; ++f)
        acc[f] = __builtin_amdgcn_mfma_f32_16x16x32_bf16(afrag[ks], wfrag[ks][f], acc[f], 0, 0, 0);

#pragma unroll
    for (int f = 0; f < 3; ++f)
#pragma unroll
      for (int i = 0; i < 4; ++i)
        red[kh * 1600 + (lh * 4 + i) * 100 + ch * 48 + f * 16 + lr] = acc[f][i];
    __syncthreads();

    // ---- epilogue ----
    {
      float xzv[2], xrv[2], xhv[2];
      xzv[0] = (float)((__hip_bfloat16*)&uz)[0];  xzv[1] = (float)((__hip_bfloat16*)&uz)[1];
      xrv[0] = (float)((__hip_bfloat16*)&ur_)[0]; xrv[1] = (float)((__hip_bfloat16*)&ur_)[1];
      xhv[0] = (float)((__hip_bfloat16*)&uh_)[0]; xhv[1] = (float)((__hip_bfloat16*)&uh_)[1];
      float hn[2];
#pragma unroll
      for (int p = 0; p < 2; ++p) {
        int jl = jl0 + p;
        float rz = red[m * 100 + jl]      + red[1600 + m * 100 + jl];
        float rr = red[m * 100 + 32 + jl] + red[1600 + m * 100 + 32 + jl];
        float rh = red[m * 100 + 64 + jl] + red[1600 + m * 100 + 64 + jl];
        rz += brz[p]; rr += brr[p]; rh += brh[p];
        float z  = 1.f / (1.f + __expf(-(xzv[p] + rz)));
        float rg = 1.f / (1.f + __expf(-(xrv[p] + rr)));
        float hh = fmaxf(xhv[p] + rg * rh, 0.f);
        hn[p] = z * hreg[p] + (1.f - z) * hh;
        hreg[p] = hn[p];
      }
      if (t < SEQ - 1) {
        __hip_bfloat16 h0 = (__hip_bfloat16)hn[0], h1 = (__hip_bfloat16)hn[1];
        unsigned int pk = (unsigned int)*(unsigned short*)&h0 |
                          ((unsigned int)*(unsigned short*)&h1 << 16);
        __hip_atomic_store(
            (unsigned int*)&nxt[(size_t)b * HID + jg0], pk,
            __ATOMIC_RELAXED, __HIP_MEMORY_SCOPE_AGENT);
      }
    }

    // ---- publish + poll (no pre-flag block barrier) ----
    if (t < SEQ - 1) {
      asm volatile("s_waitcnt vmcnt(0)" ::: "memory");  // own wave's h stores acked
      if (l == 0) {
        int old = __hip_atomic_fetch_add(&wdone, 1, __ATOMIC_RELAXED,
                                         __HIP_MEMORY_SCOPE_WORKGROUP);
        if (old == 4 * t + 3) {   // 4th wave of this step -> block done
          __hip_atomic_store(&slots[bt * 16 + jt], t + 1,
                             __ATOMIC_RELAXED, __HIP_MEMORY_SCOPE_AGENT);
        }
      }
      if (tid == 0) {
        const char* fl = (const char*)&slots[bt * 16];
        for (;;) {
          i32x4v p0, p1, p2, p3;
          asm volatile(
              "global_load_dwordx4 %0, %4, off sc0 sc1\n\t"
              "global_load_dwordx4 %1, %4, off offset:16 sc0 sc1\n\t"
              "global_load_dwordx4 %2, %4, off offset:32 sc0 sc1\n\t"
              "global_load_dwordx4 %3, %4, off offset:48 sc0 sc1\n\t"
              "s_waitcnt vmcnt(0)"
              : "=&v"(p0), "=&v"(p1), "=&v"(p2), "=&v"(p3)
              : "v"(fl)
              : "memory");
          int t1 = t + 1;
          int ok = (p0[0] >= t1) & (p0[1] >= t1) & (p0[2] >= t1) & (p0[3] >= t1) &
                   (p1[0] >= t1) & (p1[1] >= t1) & (p1[2] >= t1) & (p1[3] >= t1) &
                   (p2[0] >= t1) & (p2[1] >= t1) & (p2[2] >= t1) & (p2[3] >= t1) &
                   (p3[0] >= t1) & (p3[1] >= t1) & (p3[2] >= t1) & (p3[3] >= t1);
          if (ok) break;
        }
      }
      __syncthreads();
    }
  }

  // final fp32 h
#pragma unroll
  for (int p = 0; p < 2; ++p)
    h32[(size_t)b * HID + jg0 + p] = hreg[p];
}

// ---------------------------------------------------------------------------
// head: out[b] = h32[b][:] . Wd + bd
// ---------------------------------------------------------------------------
__global__ __launch_bounds__(64) void head_kernel(
    const float* __restrict__ h32, const float* __restrict__ Wd,
    const float* __restrict__ bd, float* __restrict__ out)
{
  int b = blockIdx.x, l = threadIdx.x;
  const float* hr = &h32[(size_t)b * HID];
  float s = 0.f;
#pragma unroll
  for (int i = 0; i < 8; ++i)
    s += hr[l + i * 64] * Wd[l + i * 64];
#pragma unroll
  for (int off = 32; off; off >>= 1) s += __shfl_down(s, off);
  if (l == 0) out[b] = s + bd[0];
}

// ---------------------------------------------------------------------------
extern "C" void kernel_launch(void* const* d_in, const int* in_sizes, int n_in,
                              void* d_out, int out_size, void* d_ws, size_t ws_size,
                              hipStream_t stream) {
  const float* x    = (const float*)d_in[0];
  const float* Wk   = (const float*)d_in[1];
  const float* Wr   = (const float*)d_in[2];
  const float* bias = (const float*)d_in[3];
  const float* Wd   = (const float*)d_in[4];
  const float* bd   = (const float*)d_in[5];
  float* out = (float*)d_out;

  char* ws = (char*)d_ws;
  size_t off = 0;
  __hip_bfloat16* xp  = (__hip_bfloat16*)(ws + off); off += (size_t)BATCH * SEQ * G3 * 2;
  __hip_bfloat16* xb  = (__hip_bfloat16*)(ws + off); off += (size_t)BATCH * SEQ * FEAT * 2;
  __hip_bfloat16* WkT = (__hip_bfloat16*)(ws + off); off += (size_t)G3 * FEAT * 2;
  __hip_bfloat16* WrT = (__hip_bfloat16*)(ws + off); off += (size_t)G3 * HID * 2;
  float*          h32 = (float*)(ws + off);          off += (size_t)BATCH * HID * 4;
  __hip_bfloat16* hb0 = (__hip_bfloat16*)(ws + off); off += (size_t)BATCH * HID * 2;
  __hip_bfloat16* hb1 = (__hip_bfloat16*)(ws + off); off += (size_t)BATCH * HID * 2;
  int*            slots = (int*)(ws + off);          off += 16 * 16 * sizeof(int);

  convert_bf16<<<(BATCH * SEQ * FEAT) / (256 * 8), 256, 0, stream>>>(x, xb, BATCH * SEQ * FEAT);
  transpose_convert<<<dim3(G3 / 32, FEAT / 32), 256, 0, stream>>>(Wk, WkT);
  transpose_convert<<<dim3(G3 / 32, HID  / 32), 256, 0, stream>>>(Wr, WrT);

  proj_mfma<<<dim3(G3 / 128, (BATCH * SEQ) / 128), 256, 0, stream>>>(xb, WkT, bias, xp);

  hipMemsetAsync(hb0, 0, (size_t)BATCH * HID * sizeof(__hip_bfloat16), stream);
  hipMemsetAsync(slots, 0, 16 * 16 * sizeof(int), stream);

  const float* br = bias + G3;
  {
    void* args[] = {(void*)&hb0, (void*)&hb1, (void*)&h32, (void*)&xp,
                    (void*)&WrT, (void*)&br, (void*)&slots};
    hipLaunchCooperativeKernel((void*)gru_persist, dim3(256), dim3(256),
                               args, 0, stream);
  }

  head_kernel<<<256, 64, 0, stream>>>(h32, Wd, bd, out);
}

// Round 9
// 677.821 us; speedup vs baseline: 1.0505x; 1.0505x over previous
//
#include <hip/hip_runtime.h>
#include <hip/hip_bf16.h>
#include <math.h>

constexpr int BATCH = 256;
constexpr int SEQ   = 128;
constexpr int FEAT  = 512;
constexpr int HID   = 512;
constexpr int G3    = 1536;

typedef __bf16 bf16x8 __attribute__((ext_vector_type(8)));
typedef float  f32x4  __attribute__((ext_vector_type(4)));
typedef int    i32x4v __attribute__((ext_vector_type(4)));

// ---------------------------------------------------------------------------
// transpose + convert: in[512][1536] f32 -> outT[1536][512] bf16
// ---------------------------------------------------------------------------
__global__ __launch_bounds__(256) void transpose_convert(
    const float* __restrict__ in, __hip_bfloat16* __restrict__ outT)
{
  __shared__ float tile[32][33];
  const int c0 = blockIdx.x * 32;
  const int r0 = blockIdx.y * 32;
  const int tid = threadIdx.x;
  {
    int row = tid >> 3, c4 = tid & 7;
    float4 v = *(const float4*)&in[(size_t)(r0 + row) * G3 + c0 + c4 * 4];
    tile[row][c4 * 4 + 0] = v.x;
    tile[row][c4 * 4 + 1] = v.y;
    tile[row][c4 * 4 + 2] = v.z;
    tile[row][c4 * 4 + 3] = v.w;
  }
  __syncthreads();
  {
    int rowT = tid >> 3, c4 = tid & 7;
    __hip_bfloat16 o[4];
#pragma unroll
    for (int e = 0; e < 4; ++e)
      o[e] = (__hip_bfloat16)tile[c4 * 4 + e][rowT];
    *(int2*)&outT[(size_t)(c0 + rowT) * FEAT + r0 + c4 * 4] = *(int2*)o;
  }
}

// ---------------------------------------------------------------------------
// Persistent FUSED GRU: per step computes x(t)@Wk AND h(t)@Wr.
//   Grid 256: blockIdx.x = jt*16 + bt. Group = same bt (16 blocks).
//   Waves (kh, ch): K-half x j-half. Per wave per step: 48 MFMA.
//   Wr: register-pinned (96 VGPR). Wk: LDS, chunk-XOR swizzled (98 KB).
//   h exchange: batched coherent dwordx4 loads / relaxed u32 stores (R7).
//   Barrier: R7's proven leader flag + s_sleep poll.
// Accumulators: z,r merged (x+h proj); candidate gate split (xh, rh).
// ---------------------------------------------------------------------------
__global__ __launch_bounds__(256, 1) void gru_persist(
    __hip_bfloat16* __restrict__ hbA, __hip_bfloat16* __restrict__ hbB,
    float* __restrict__ h32,
    const float* __restrict__ x,             // [B][T][F] fp32
    const __hip_bfloat16* __restrict__ WkT,  // [1536][512] bf16
    const __hip_bfloat16* __restrict__ WrT,  // [1536][512] bf16
    const float* __restrict__ bias,          // [2][1536]
    int* slots)                               // [16][16] ints
{
  extern __shared__ char smem[];
  __hip_bfloat16* Wk_s = (__hip_bfloat16*)smem;          // [96][512]  98304 B
  float*          red  = (float*)(smem + 98304);         // [2][4][16][33] 16896 B

  const int tid = threadIdx.x;
  const int bt = blockIdx.x & 15;
  const int jt = blockIdx.x >> 4;
  const int wave = tid >> 6, l = tid & 63;
  const int kh = wave & 1, ch = wave >> 1;
  const int lr = l & 15, lh = l >> 4;

  // ---- one-time: Wk slice -> LDS (chunk-XOR swizzle; row = gate*32+jl) ----
#pragma unroll
  for (int i = 0; i < 24; ++i) {
    int q = tid + i * 256;            // 0..6143 16B-chunks
    int row = q >> 6;                 // 0..95
    int cpos = q & 63;                // LDS chunk position
    int gch = cpos ^ (row & 7);       // global chunk held at cpos
    int n = (row >> 5) * HID + jt * 32 + (row & 31);
    *(int4*)&Wk_s[row * 512 + cpos * 8] =
        *(const int4*)&WkT[(size_t)n * HID + gch * 8];
  }

  // ---- one-time: Wr fragments -> registers, pinned ----
  // row_f = f*32 + ch*16 + lr  (gate f, local j = ch*16+lr)
  bf16x8 wfrag[8][3];
#pragma unroll
  for (int f = 0; f < 3; ++f) {
    int n = f * HID + jt * 32 + ch * 16 + lr;
    const __hip_bfloat16* wp = &WrT[(size_t)n * HID + kh * 256 + lh * 8];
#pragma unroll
    for (int ks = 0; ks < 8; ++ks)
      wfrag[ks][f] = *(const bf16x8*)&wp[ks * 32];
  }
  asm volatile(""
      : "+v"(wfrag[0][0]), "+v"(wfrag[0][1]), "+v"(wfrag[0][2]),
        "+v"(wfrag[1][0]), "+v"(wfrag[1][1]), "+v"(wfrag[1][2]),
        "+v"(wfrag[2][0]), "+v"(wfrag[2][1]), "+v"(wfrag[2][2]),
        "+v"(wfrag[3][0]), "+v"(wfrag[3][1]), "+v"(wfrag[3][2]),
        "+v"(wfrag[4][0]), "+v"(wfrag[4][1]), "+v"(wfrag[4][2]),
        "+v"(wfrag[5][0]), "+v"(wfrag[5][1]), "+v"(wfrag[5][2]),
        "+v"(wfrag[6][0]), "+v"(wfrag[6][1]), "+v"(wfrag[6][2]),
        "+v"(wfrag[7][0]), "+v"(wfrag[7][1]), "+v"(wfrag[7][2]));

  // ---- per-thread epilogue ownership: (m, q4) -> j pair {q4*2, q4*2+1} ----
  const int m = tid >> 4, q4 = tid & 15;
  const int b = bt * 16 + m;
  const int jl0 = q4 * 2;
  const int jg0 = jt * 32 + jl0;
  float bzr[2], brr_[2], bih[2], brh[2], hreg[2];
#pragma unroll
  for (int p = 0; p < 2; ++p) {
    int j = jg0 + p;
    bzr[p]  = bias[j] + bias[G3 + j];                 // z gate: bi+br merged
    brr_[p] = bias[HID + j] + bias[G3 + HID + j];     // r gate: bi+br merged
    bih[p]  = bias[2 * HID + j];                      // candidate: bi alone
    brh[p]  = bias[G3 + 2 * HID + j];                 // candidate: br alone
    hreg[p] = 0.f;
  }
  __syncthreads();   // Wk_s ready

  // per-lane bases
  const float* xrow = x + (size_t)(bt * 16 + lr) * SEQ * FEAT + kh * 256 + lh * 8;
  const char* baseA = (const char*)hbA + ((size_t)(bt * 16 + lr) * HID + kh * 256 + lh * 8) * 2;
  const char* baseB = (const char*)hbB + ((size_t)(bt * 16 + lr) * HID + kh * 256 + lh * 8) * 2;

  for (int t = 0; t < SEQ; ++t) {
    const char* hp = (t & 1) ? baseB : baseA;
    __hip_bfloat16* nxt = (t & 1) ? hbA : hbB;

    // ---- issue x(t) fragment loads (plain, cached) ----
    const float* xr = xrow + (size_t)t * FEAT;
    float4 xa[8], xc[8];
#pragma unroll
    for (int ks = 0; ks < 8; ++ks) {
      xa[ks] = *(const float4*)&xr[ks * 32];
      xc[ks] = *(const float4*)&xr[ks * 32 + 4];
    }

    // ---- h fragments: 8 batched coherent 16B loads, ONE waitcnt ----
    i32x4v r0, r1, r2, r3, r4, r5, r6, r7;
    asm volatile(
        "global_load_dwordx4 %0, %8, off sc0 sc1\n\t"
        "global_load_dwordx4 %1, %8, off offset:64 sc0 sc1\n\t"
        "global_load_dwordx4 %2, %8, off offset:128 sc0 sc1\n\t"
        "global_load_dwordx4 %3, %8, off offset:192 sc0 sc1\n\t"
        "global_load_dwordx4 %4, %8, off offset:256 sc0 sc1\n\t"
        "global_load_dwordx4 %5, %8, off offset:320 sc0 sc1\n\t"
        "global_load_dwordx4 %6, %8, off offset:384 sc0 sc1\n\t"
        "global_load_dwordx4 %7, %8, off offset:448 sc0 sc1\n\t"
        "s_waitcnt vmcnt(0)"
        : "=&v"(r0), "=&v"(r1), "=&v"(r2), "=&v"(r3),
          "=&v"(r4), "=&v"(r5), "=&v"(r6), "=&v"(r7)
        : "v"(hp)
        : "memory");
    union { i32x4v q; bf16x8 v; } u0, u1, u2, u3, u4, u5, u6, u7;
    u0.q = r0; u1.q = r1; u2.q = r2; u3.q = r3;
    u4.q = r4; u5.q = r5; u6.q = r6; u7.q = r7;
    bf16x8 afrag[8] = {u0.v, u1.v, u2.v, u3.v, u4.v, u5.v, u6.v, u7.v};

    // ---- convert x fragments to bf16 ----
    bf16x8 xfrag[8];
#pragma unroll
    for (int ks = 0; ks < 8; ++ks) {
      __hip_bfloat16 o[8];
      o[0] = (__hip_bfloat16)xa[ks].x; o[1] = (__hip_bfloat16)xa[ks].y;
      o[2] = (__hip_bfloat16)xa[ks].z; o[3] = (__hip_bfloat16)xa[ks].w;
      o[4] = (__hip_bfloat16)xc[ks].x; o[5] = (__hip_bfloat16)xc[ks].y;
      o[6] = (__hip_bfloat16)xc[ks].z; o[7] = (__hip_bfloat16)xc[ks].w;
      xfrag[ks] = *(bf16x8*)o;
    }

    // ---- MFMA: z,r merged accumulators; candidate split (xh, rh) ----
    f32x4 az = {}, ar = {}, axh = {}, arh = {};
    const int swz = lr & 7;
#pragma unroll
    for (int ks = 0; ks < 8; ++ks) {
      int cbase = kh * 32 + ks * 4 + lh;
      bf16x8 k0 = *(const bf16x8*)&Wk_s[(0 * 32 + ch * 16 + lr) * 512 + ((cbase ^ swz) * 8)];
      bf16x8 k1 = *(const bf16x8*)&Wk_s[(1 * 32 + ch * 16 + lr) * 512 + ((cbase ^ swz) * 8)];
      bf16x8 k2 = *(const bf16x8*)&Wk_s[(2 * 32 + ch * 16 + lr) * 512 + ((cbase ^ swz) * 8)];
      az  = __builtin_amdgcn_mfma_f32_16x16x32_bf16(afrag[ks], wfrag[ks][0], az, 0, 0, 0);
      az  = __builtin_amdgcn_mfma_f32_16x16x32_bf16(xfrag[ks], k0,           az, 0, 0, 0);
      ar  = __builtin_amdgcn_mfma_f32_16x16x32_bf16(afrag[ks], wfrag[ks][1], ar, 0, 0, 0);
      ar  = __builtin_amdgcn_mfma_f32_16x16x32_bf16(xfrag[ks], k1,           ar, 0, 0, 0);
      arh = __builtin_amdgcn_mfma_f32_16x16x32_bf16(afrag[ks], wfrag[ks][2], arh, 0, 0, 0);
      axh = __builtin_amdgcn_mfma_f32_16x16x32_bf16(xfrag[ks], k2,           axh, 0, 0, 0);
    }

    // ---- partials -> LDS: red[kh][class][row][col33] ----
    {
      int col = ch * 16 + lr;
#pragma unroll
      for (int i = 0; i < 4; ++i) {
        int row = lh * 4 + i;
        red[((kh * 4 + 0) * 16 + row) * 33 + col] = az[i];
        red[((kh * 4 + 1) * 16 + row) * 33 + col] = ar[i];
        red[((kh * 4 + 2) * 16 + row) * 33 + col] = axh[i];
        red[((kh * 4 + 3) * 16 + row) * 33 + col] = arh[i];
      }
    }
    __syncthreads();

    // ---- epilogue: 2 consecutive j per thread ----
    {
      float hn[2];
#pragma unroll
      for (int p = 0; p < 2; ++p) {
        int jl = jl0 + p;
        float vz  = red[((0 * 4 + 0) * 16 + m) * 33 + jl] + red[((1 * 4 + 0) * 16 + m) * 33 + jl];
        float vr  = red[((0 * 4 + 1) * 16 + m) * 33 + jl] + red[((1 * 4 + 1) * 16 + m) * 33 + jl];
        float vxh = red[((0 * 4 + 2) * 16 + m) * 33 + jl] + red[((1 * 4 + 2) * 16 + m) * 33 + jl];
        float vrh = red[((0 * 4 + 3) * 16 + m) * 33 + jl] + red[((1 * 4 + 3) * 16 + m) * 33 + jl];
        float z  = 1.f / (1.f + __expf(-(vz + bzr[p])));
        float rg = 1.f / (1.f + __expf(-(vr + brr_[p])));
        float hh = fmaxf(vxh + bih[p] + rg * (vrh + brh[p]), 0.f);
        hn[p] = z * hreg[p] + (1.f - z) * hh;
        hreg[p] = hn[p];
      }
      if (t < SEQ - 1) {
        __hip_bfloat16 h0 = (__hip_bfloat16)hn[0], h1 = (__hip_bfloat16)hn[1];
        unsigned int pk = (unsigned int)*(unsigned short*)&h0 |
                          ((unsigned int)*(unsigned short*)&h1 << 16);
        __hip_atomic_store(
            (unsigned int*)&nxt[(size_t)b * HID + jg0], pk,
            __ATOMIC_RELAXED, __HIP_MEMORY_SCOPE_AGENT);
      }
    }

    // ---- group barrier: R7 proven (pre-flag barrier, leader flag+poll) ----
    if (t < SEQ - 1) {
      __syncthreads();   // drains all waves' vmcnt -> h stores visible
      if (tid == 0) {
        __hip_atomic_store(&slots[bt * 16 + jt], t + 1,
                           __ATOMIC_RELAXED, __HIP_MEMORY_SCOPE_AGENT);
        const char* fl = (const char*)&slots[bt * 16];
        for (;;) {
          i32x4v p0, p1, p2, p3;
          asm volatile(
              "global_load_dwordx4 %0, %4, off sc0 sc1\n\t"
              "global_load_dwordx4 %1, %4, off offset:16 sc0 sc1\n\t"
              "global_load_dwordx4 %2, %4, off offset:32 sc0 sc1\n\t"
              "global_load_dwordx4 %3, %4, off offset:48 sc0 sc1\n\t"
              "s_waitcnt vmcnt(0)"
              : "=&v"(p0), "=&v"(p1), "=&v"(p2), "=&v"(p3)
              : "v"(fl)
              : "memory");
          int t1 = t + 1;
          int ok = (p0[0] >= t1) & (p0[1] >= t1) & (p0[2] >= t1) & (p0[3] >= t1) &
                   (p1[0] >= t1) & (p1[1] >= t1) & (p1[2] >= t1) & (p1[3] >= t1) &
                   (p2[0] >= t1) & (p2[1] >= t1) & (p2[2] >= t1) & (p2[3] >= t1) &
                   (p3[0] >= t1) & (p3[1] >= t1) & (p3[2] >= t1) & (p3[3] >= t1);
          if (ok) break;
          __builtin_amdgcn_s_sleep(1);
        }
      }
      __syncthreads();
    }
  }

  // final fp32 h
#pragma unroll
  for (int p = 0; p < 2; ++p)
    h32[(size_t)b * HID + jg0 + p] = hreg[p];
}

// ---------------------------------------------------------------------------
// head: out[b] = h32[b][:] . Wd + bd
// ---------------------------------------------------------------------------
__global__ __launch_bounds__(64) void head_kernel(
    const float* __restrict__ h32, const float* __restrict__ Wd,
    const float* __restrict__ bd, float* __restrict__ out)
{
  int b = blockIdx.x, l = threadIdx.x;
  const float* hr = &h32[(size_t)b * HID];
  float s = 0.f;
#pragma unroll
  for (int i = 0; i < 8; ++i)
    s += hr[l + i * 64] * Wd[l + i * 64];
#pragma unroll
  for (int off = 32; off; off >>= 1) s += __shfl_down(s, off);
  if (l == 0) out[b] = s + bd[0];
}

// ---------------------------------------------------------------------------
extern "C" void kernel_launch(void* const* d_in, const int* in_sizes, int n_in,
                              void* d_out, int out_size, void* d_ws, size_t ws_size,
                              hipStream_t stream) {
  const float* x    = (const float*)d_in[0];
  const float* Wk   = (const float*)d_in[1];
  const float* Wr   = (const float*)d_in[2];
  const float* bias = (const float*)d_in[3];
  const float* Wd   = (const float*)d_in[4];
  const float* bd   = (const float*)d_in[5];
  float* out = (float*)d_out;

  char* ws = (char*)d_ws;
  size_t off = 0;
  __hip_bfloat16* WkT = (__hip_bfloat16*)(ws + off); off += (size_t)G3 * FEAT * 2;
  __hip_bfloat16* WrT = (__hip_bfloat16*)(ws + off); off += (size_t)G3 * HID * 2;
  float*          h32 = (float*)(ws + off);          off += (size_t)BATCH * HID * 4;
  __hip_bfloat16* hb0 = (__hip_bfloat16*)(ws + off); off += (size_t)BATCH * HID * 2;
  __hip_bfloat16* hb1 = (__hip_bfloat16*)(ws + off); off += (size_t)BATCH * HID * 2;
  int*            slots = (int*)(ws + off);          off += 16 * 16 * sizeof(int);

  transpose_convert<<<dim3(G3 / 32, FEAT / 32), 256, 0, stream>>>(Wk, WkT);
  transpose_convert<<<dim3(G3 / 32, HID  / 32), 256, 0, stream>>>(Wr, WrT);

  hipMemsetAsync(hb0, 0, (size_t)BATCH * HID * sizeof(__hip_bfloat16), stream);
  hipMemsetAsync(slots, 0, 16 * 16 * sizeof(int), stream);

  const size_t lds_bytes = 98304 + 16896;  // Wk_s + red
  hipFuncSetAttribute((const void*)gru_persist,
                      hipFuncAttributeMaxDynamicSharedMemorySize, (int)lds_bytes);
  {
    void* args[] = {(void*)&hb0, (void*)&hb1, (void*)&h32, (void*)&x,
                    (void*)&WkT, (void*)&WrT, (void*)&bias, (void*)&slots};
    hipLaunchCooperativeKernel((void*)gru_persist, dim3(256), dim3(256),
                               args, (unsigned)lds_bytes, stream);
  }

  head_kernel<<<256, 64, 0, stream>>>(h32, Wd, bd, out);
}

// Round 11
// 646.326 us; speedup vs baseline: 1.1017x; 1.0487x over previous
//
#include <hip/hip_runtime.h>
#include <hip/hip_bf16.h>
#include <math.h>

constexpr int BATCH = 256;
constexpr int SEQ   = 128;
constexpr int FEAT  = 512;
constexpr int HID   = 512;
constexpr int G3    = 1536;

typedef __bf16 bf16x8 __attribute__((ext_vector_type(8)));
typedef float  f32x4  __attribute__((ext_vector_type(4)));
typedef int    i32x4v __attribute__((ext_vector_type(4)));

// ---------------------------------------------------------------------------
// fp32 -> bf16 convert (vectorized, 8/thread)
// ---------------------------------------------------------------------------
__global__ __launch_bounds__(256) void convert_bf16(
    const float* __restrict__ in, __hip_bfloat16* __restrict__ out, int n)
{
  int i = (blockIdx.x * 256 + threadIdx.x) * 8;
  if (i >= n) return;
  float4 v0 = *(const float4*)&in[i];
  float4 v1 = *(const float4*)&in[i + 4];
  __hip_bfloat16 o[8];
  o[0] = (__hip_bfloat16)v0.x; o[1] = (__hip_bfloat16)v0.y;
  o[2] = (__hip_bfloat16)v0.z; o[3] = (__hip_bfloat16)v0.w;
  o[4] = (__hip_bfloat16)v1.x; o[5] = (__hip_bfloat16)v1.y;
  o[6] = (__hip_bfloat16)v1.z; o[7] = (__hip_bfloat16)v1.w;
  *(int4*)&out[i] = *(int4*)o;
}

// ---------------------------------------------------------------------------
// transpose + convert: in[512][1536] f32 -> outT[1536][512] bf16
// ---------------------------------------------------------------------------
__global__ __launch_bounds__(256) void transpose_convert(
    const float* __restrict__ in, __hip_bfloat16* __restrict__ outT)
{
  __shared__ float tile[32][33];
  const int c0 = blockIdx.x * 32;
  const int r0 = blockIdx.y * 32;
  const int tid = threadIdx.x;
  {
    int row = tid >> 3, c4 = tid & 7;
    float4 v = *(const float4*)&in[(size_t)(r0 + row) * G3 + c0 + c4 * 4];
    tile[row][c4 * 4 + 0] = v.x;
    tile[row][c4 * 4 + 1] = v.y;
    tile[row][c4 * 4 + 2] = v.z;
    tile[row][c4 * 4 + 3] = v.w;
  }
  __syncthreads();
  {
    int rowT = tid >> 3, c4 = tid & 7;
    __hip_bfloat16 o[4];
#pragma unroll
    for (int e = 0; e < 4; ++e)
      o[e] = (__hip_bfloat16)tile[c4 * 4 + e][rowT];
    *(int2*)&outT[(size_t)(c0 + rowT) * FEAT + r0 + c4 * 4] = *(int2*)o;
  }
}

// ---------------------------------------------------------------------------
// proj: 128x128 tile, BK=64, 2-phase double-buffered global_load_lds with
// XOR source/read swizzle (0 bank conflicts). Unchanged from R7.
// ---------------------------------------------------------------------------
__global__ __launch_bounds__(256) void proj_mfma(
    const __hip_bfloat16* __restrict__ xb, const __hip_bfloat16* __restrict__ WkT,
    const float* __restrict__ bias, __hip_bfloat16* __restrict__ xp)
{
  __shared__ __align__(16) __hip_bfloat16 As[2][128 * 64];
  __shared__ __align__(16) __hip_bfloat16 Bs[2][128 * 64];

  const int tid = threadIdx.x;
  const int wave = tid >> 6, l = tid & 63;
  const int wm = wave >> 1, wn = wave & 1;
  const int m0 = blockIdx.y * 128;
  const int n0 = blockIdx.x * 128;
  const int lr = l & 15, lh = l >> 4;
  const int swz = lr & 7;

  const int srow = l >> 3;
  const int schk = l & 7;
  const int wrow = wave * 32;

  f32x4 acc[4][4] = {};

#define PROJ_STAGE(K0, SEL)                                                      \
  {                                                                              \
    _Pragma("unroll")                                                            \
    for (int i = 0; i < 4; ++i) {                                                \
      int r = wrow + i * 8 + srow;                                               \
      const __hip_bfloat16* srcA =                                               \
          &xb[(size_t)(m0 + r) * FEAT + (K0) + ((schk ^ srow) * 8)];             \
      __builtin_amdgcn_global_load_lds(                                          \
          (const __attribute__((address_space(1))) void*)srcA,                   \
          (__attribute__((address_space(3))) void*)&As[SEL][(wrow + i * 8) * 64],\
          16, 0, 0);                                                             \
    }                                                                            \
    _Pragma("unroll")                                                            \
    for (int i = 0; i < 4; ++i) {                                                \
      int r = wrow + i * 8 + srow;                                               \
      const __hip_bfloat16* srcB =                                               \
          &WkT[(size_t)(n0 + r) * FEAT + (K0) + ((schk ^ srow) * 8)];            \
      __builtin_amdgcn_global_load_lds(                                          \
          (const __attribute__((address_space(1))) void*)srcB,                   \
          (__attribute__((address_space(3))) void*)&Bs[SEL][(wrow + i * 8) * 64],\
          16, 0, 0);                                                             \
    }                                                                            \
  }

  PROJ_STAGE(0, 0);
  __syncthreads();

  int cur = 0;
  for (int kt = 0; kt < 8; ++kt) {
    if (kt < 7) PROJ_STAGE((kt + 1) * 64, cur ^ 1);

#pragma unroll
    for (int ks = 0; ks < 2; ++ks) {
      bf16x8 a[4], b[4];
#pragma unroll
      for (int i = 0; i < 4; ++i) {
        int row = wm * 64 + i * 16 + lr;
        a[i] = *(const bf16x8*)&As[cur][row * 64 + (((ks * 4 + lh) ^ swz) * 8)];
      }
#pragma unroll
      for (int j = 0; j < 4; ++j) {
        int row = wn * 64 + j * 16 + lr;
        b[j] = *(const bf16x8*)&Bs[cur][row * 64 + (((ks * 4 + lh) ^ swz) * 8)];
      }
#pragma unroll
      for (int i = 0; i < 4; ++i)
#pragma unroll
        for (int j = 0; j < 4; ++j)
          acc[i][j] = __builtin_amdgcn_mfma_f32_16x16x32_bf16(a[i], b[j], acc[i][j], 0, 0, 0);
    }
    __syncthreads();
    cur ^= 1;
  }

  float bv[4];
#pragma unroll
  for (int j = 0; j < 4; ++j)
    bv[j] = bias[n0 + wn * 64 + j * 16 + lr];
#pragma unroll
  for (int i = 0; i < 4; ++i)
#pragma unroll
    for (int j = 0; j < 4; ++j) {
      int n = n0 + wn * 64 + j * 16 + lr;
#pragma unroll
      for (int r = 0; r < 4; ++r) {
        int m = m0 + wm * 64 + i * 16 + lh * 4 + r;
        xp[(size_t)m * G3 + n] = (__hip_bfloat16)(acc[i][j][r] + bv[j]);
      }
    }
#undef PROJ_STAGE
}

// ---------------------------------------------------------------------------
// Persistent GRU recurrence, v7 = R7 protocol (sc0 sc1 everywhere, proven)
// with a shortened sync chain:
//   - per-wave publish: own vmcnt(0) drain -> LDS ds_add; 4th wave stores
//     the block flag (replaces pre-flag __syncthreads + leader store).
//   - all-wave sleep-throttled poll of the 64-B flag line (replaces leader
//     poll + post-flag __syncthreads).
//   Safety: a wave passes poll(t) only when flag(t+1) is set, which requires
//   its own block's 4 waves to have finished the epilogue -> red[] reuse at
//   t+1 is ordered without block barriers. Only the red-write->epilogue-read
//   __syncthreads remains.
// Grid 256: blockIdx.x = jt*16 + bt.
// ---------------------------------------------------------------------------
__global__ __launch_bounds__(256, 1) void gru_persist(
    __hip_bfloat16* __restrict__ hbA, __hip_bfloat16* __restrict__ hbB,
    float* __restrict__ h32,
    const __hip_bfloat16* __restrict__ xp,
    const __hip_bfloat16* __restrict__ WrT,
    const float* __restrict__ br,
    int* slots)                               // [16][16] ints
{
  __shared__ float red[2 * 16 * 100];
  __shared__ int wdone;

  const int tid = threadIdx.x;
  const int bt = blockIdx.x & 15;
  const int jt = blockIdx.x >> 4;
  const int wave = tid >> 6, l = tid & 63;
  const int kh = wave & 1, ch = wave >> 1;
  const int lr = l & 15, lh = l >> 4;

  // ---- one-time: W fragments -> registers (24 x 16B per lane), pinned ----
  bf16x8 wfrag[8][3];
#pragma unroll
  for (int f = 0; f < 3; ++f) {
    int r = ch * 48 + f * 16 + lr;
    int n = (r >> 5) * HID + jt * 32 + (r & 31);
    const __hip_bfloat16* wp = &WrT[(size_t)n * HID + kh * 256 + lh * 8];
#pragma unroll
    for (int ks = 0; ks < 8; ++ks)
      wfrag[ks][f] = *(const bf16x8*)&wp[ks * 32];
  }
  asm volatile(""
      : "+v"(wfrag[0][0]), "+v"(wfrag[0][1]), "+v"(wfrag[0][2]),
        "+v"(wfrag[1][0]), "+v"(wfrag[1][1]), "+v"(wfrag[1][2]),
        "+v"(wfrag[2][0]), "+v"(wfrag[2][1]), "+v"(wfrag[2][2]),
        "+v"(wfrag[3][0]), "+v"(wfrag[3][1]), "+v"(wfrag[3][2]),
        "+v"(wfrag[4][0]), "+v"(wfrag[4][1]), "+v"(wfrag[4][2]),
        "+v"(wfrag[5][0]), "+v"(wfrag[5][1]), "+v"(wfrag[5][2]),
        "+v"(wfrag[6][0]), "+v"(wfrag[6][1]), "+v"(wfrag[6][2]),
        "+v"(wfrag[7][0]), "+v"(wfrag[7][1]), "+v"(wfrag[7][2]));

  // ---- per-thread epilogue ownership ----
  const int m = tid >> 4, q4 = tid & 15;
  const int b = bt * 16 + m;
  const int jl0 = q4 * 2;
  const int jg0 = jt * 32 + jl0;
  float brz[2], brr[2], brh[2], hreg[2];
#pragma unroll
  for (int p = 0; p < 2; ++p) {
    brz[p] = br[jg0 + p];
    brr[p] = br[HID + jg0 + p];
    brh[p] = br[2 * HID + jg0 + p];
    hreg[p] = 0.f;
  }

  if (tid == 0) wdone = 0;   // visible before first use (first red barrier)

  // preload xp for t=0 (u32 = 2 consecutive bf16)
  unsigned int uz, ur_, uh_;
  {
    const __hip_bfloat16* xq = &xp[((size_t)b * SEQ + 0) * G3 + jg0];
    uz  = *(const unsigned int*)&xq[0];
    ur_ = *(const unsigned int*)&xq[HID];
    uh_ = *(const unsigned int*)&xq[2 * HID];
  }

  // per-lane h-fragment base (bytes)
  const char* baseA = (const char*)hbA + ((size_t)(bt * 16 + lr) * HID + kh * 256 + lh * 8) * 2;
  const char* baseB = (const char*)hbB + ((size_t)(bt * 16 + lr) * HID + kh * 256 + lh * 8) * 2;

  for (int t = 0; t < SEQ; ++t) {
    const char* hp = (t & 1) ? baseB : baseA;
    __hip_bfloat16* nxt = (t & 1) ? hbA : hbB;

    // ---- h fragments: 8 batched coherent 16B loads, ONE waitcnt ----
    i32x4v r0, r1, r2, r3, r4, r5, r6, r7;
    asm volatile(
        "global_load_dwordx4 %0, %8, off sc0 sc1\n\t"
        "global_load_dwordx4 %1, %8, off offset:64 sc0 sc1\n\t"
        "global_load_dwordx4 %2, %8, off offset:128 sc0 sc1\n\t"
        "global_load_dwordx4 %3, %8, off offset:192 sc0 sc1\n\t"
        "global_load_dwordx4 %4, %8, off offset:256 sc0 sc1\n\t"
        "global_load_dwordx4 %5, %8, off offset:320 sc0 sc1\n\t"
        "global_load_dwordx4 %6, %8, off offset:384 sc0 sc1\n\t"
        "global_load_dwordx4 %7, %8, off offset:448 sc0 sc1\n\t"
        "s_waitcnt vmcnt(0)"
        : "=&v"(r0), "=&v"(r1), "=&v"(r2), "=&v"(r3),
          "=&v"(r4), "=&v"(r5), "=&v"(r6), "=&v"(r7)
        : "v"(hp)
        : "memory");
    union { i32x4v q; bf16x8 v; } u0, u1, u2, u3, u4, u5, u6, u7;
    u0.q = r0; u1.q = r1; u2.q = r2; u3.q = r3;
    u4.q = r4; u5.q = r5; u6.q = r6; u7.q = r7;
    bf16x8 afrag[8] = {u0.v, u1.v, u2.v, u3.v, u4.v, u5.v, u6.v, u7.v};

    // ---- MFMA: pure register operands ----
    f32x4 acc[3] = {};
#pragma unroll
    for (int ks = 0; ks < 8; ++ks)
#pragma unroll
      for (int f = 0; f < 3; ++f)
        acc[f] = __builtin_amdgcn_mfma_f32_16x16x32_bf16(afrag[ks], wfrag[ks][f], acc[f], 0, 0, 0);

#pragma unroll
    for (int f = 0; f < 3; ++f)
#pragma unroll
      for (int i = 0; i < 4; ++i)
        red[kh * 1600 + (lh * 4 + i) * 100 + ch * 48 + f * 16 + lr] = acc[f][i];
    __syncthreads();   // the ONE structural barrier: red write -> red read

    // ---- epilogue ----
    {
      float xzv[2], xrv[2], xhv[2];
      xzv[0] = (float)((__hip_bfloat16*)&uz)[0];  xzv[1] = (float)((__hip_bfloat16*)&uz)[1];
      xrv[0] = (float)((__hip_bfloat16*)&ur_)[0]; xrv[1] = (float)((__hip_bfloat16*)&ur_)[1];
      xhv[0] = (float)((__hip_bfloat16*)&uh_)[0]; xhv[1] = (float)((__hip_bfloat16*)&uh_)[1];
      float hn[2];
#pragma unroll
      for (int p = 0; p < 2; ++p) {
        int jl = jl0 + p;
        float rz = red[m * 100 + jl]      + red[1600 + m * 100 + jl];
        float rr = red[m * 100 + 32 + jl] + red[1600 + m * 100 + 32 + jl];
        float rh = red[m * 100 + 64 + jl] + red[1600 + m * 100 + 64 + jl];
        rz += brz[p]; rr += brr[p]; rh += brh[p];
        float z  = 1.f / (1.f + __expf(-(xzv[p] + rz)));
        float rg = 1.f / (1.f + __expf(-(xrv[p] + rr)));
        float hh = fmaxf(xhv[p] + rg * rh, 0.f);
        hn[p] = z * hreg[p] + (1.f - z) * hh;
        hreg[p] = hn[p];
      }
      if (t < SEQ - 1) {
        __hip_bfloat16 h0 = (__hip_bfloat16)hn[0], h1 = (__hip_bfloat16)hn[1];
        unsigned int pk = (unsigned int)*(unsigned short*)&h0 |
                          ((unsigned int)*(unsigned short*)&h1 << 16);
        __hip_atomic_store(
            (unsigned int*)&nxt[(size_t)b * HID + jg0], pk,
            __ATOMIC_RELAXED, __HIP_MEMORY_SCOPE_AGENT);
      }
    }

    // ---- publish (per-wave) + all-wave throttled poll ----
    if (t < SEQ - 1) {
      asm volatile("s_waitcnt vmcnt(0)" ::: "memory");  // own h stores acked
      if (l == 0) {
        int old = __hip_atomic_fetch_add(&wdone, 1, __ATOMIC_RELAXED,
                                         __HIP_MEMORY_SCOPE_WORKGROUP);
        if (old == 4 * t + 3) {   // last of this block's 4 waves this step
          __hip_atomic_store(&slots[bt * 16 + jt], t + 1,
                             __ATOMIC_RELAXED, __HIP_MEMORY_SCOPE_AGENT);
        }
      }

      // xp(t+1) prefetch — issued now, completes under the poll below
      {
        const __hip_bfloat16* xq = &xp[((size_t)b * SEQ + t + 1) * G3 + jg0];
        uz  = *(const unsigned int*)&xq[0];
        ur_ = *(const unsigned int*)&xq[HID];
        uh_ = *(const unsigned int*)&xq[2 * HID];
      }

      // all-wave poll of the group's 64-B flag line (broadcast-coalesced)
      const char* fl = (const char*)&slots[bt * 16];
      for (;;) {
        i32x4v p0, p1, p2, p3;
        asm volatile(
            "global_load_dwordx4 %0, %4, off sc0 sc1\n\t"
            "global_load_dwordx4 %1, %4, off offset:16 sc0 sc1\n\t"
            "global_load_dwordx4 %2, %4, off offset:32 sc0 sc1\n\t"
            "global_load_dwordx4 %3, %4, off offset:48 sc0 sc1\n\t"
            "s_waitcnt vmcnt(0)"
            : "=&v"(p0), "=&v"(p1), "=&v"(p2), "=&v"(p3)
            : "v"(fl)
            : "memory");
        int t1 = t + 1;
        int ok = (p0[0] >= t1) & (p0[1] >= t1) & (p0[2] >= t1) & (p0[3] >= t1) &
                 (p1[0] >= t1) & (p1[1] >= t1) & (p1[2] >= t1) & (p1[3] >= t1) &
                 (p2[0] >= t1) & (p2[1] >= t1) & (p2[2] >= t1) & (p2[3] >= t1) &
                 (p3[0] >= t1) & (p3[1] >= t1) & (p3[2] >= t1) & (p3[3] >= t1);
        if (ok) break;
        __builtin_amdgcn_s_sleep(1);
      }
    }
  }

  // final fp32 h
#pragma unroll
  for (int p = 0; p < 2; ++p)
    h32[(size_t)b * HID + jg0 + p] = hreg[p];
}

// ---------------------------------------------------------------------------
// head: out[b] = h32[b][:] . Wd + bd
// ---------------------------------------------------------------------------
__global__ __launch_bounds__(64) void head_kernel(
    const float* __restrict__ h32, const float* __restrict__ Wd,
    const float* __restrict__ bd, float* __restrict__ out)
{
  int b = blockIdx.x, l = threadIdx.x;
  const float* hr = &h32[(size_t)b * HID];
  float s = 0.f;
#pragma unroll
  for (int i = 0; i < 8; ++i)
    s += hr[l + i * 64] * Wd[l + i * 64];
#pragma unroll
  for (int off = 32; off; off >>= 1) s += __shfl_down(s, off);
  if (l == 0) out[b] = s + bd[0];
}

// ---------------------------------------------------------------------------
extern "C" void kernel_launch(void* const* d_in, const int* in_sizes, int n_in,
                              void* d_out, int out_size, void* d_ws, size_t ws_size,
                              hipStream_t stream) {
  const float* x    = (const float*)d_in[0];
  const float* Wk   = (const float*)d_in[1];
  const float* Wr   = (const float*)d_in[2];
  const float* bias = (const float*)d_in[3];
  const float* Wd   = (const float*)d_in[4];
  const float* bd   = (const float*)d_in[5];
  float* out = (float*)d_out;

  char* ws = (char*)d_ws;
  size_t off = 0;
  __hip_bfloat16* xp  = (__hip_bfloat16*)(ws + off); off += (size_t)BATCH * SEQ * G3 * 2;
  __hip_bfloat16* xb  = (__hip_bfloat16*)(ws + off); off += (size_t)BATCH * SEQ * FEAT * 2;
  __hip_bfloat16* WkT = (__hip_bfloat16*)(ws + off); off += (size_t)G3 * FEAT * 2;
  __hip_bfloat16* WrT = (__hip_bfloat16*)(ws + off); off += (size_t)G3 * HID * 2;
  float*          h32 = (float*)(ws + off);          off += (size_t)BATCH * HID * 4;
  __hip_bfloat16* hb0 = (__hip_bfloat16*)(ws + off); off += (size_t)BATCH * HID * 2;
  __hip_bfloat16* hb1 = (__hip_bfloat16*)(ws + off); off += (size_t)BATCH * HID * 2;
  int*            slots = (int*)(ws + off);          off += 16 * 16 * sizeof(int);

  convert_bf16<<<(BATCH * SEQ * FEAT) / (256 * 8), 256, 0, stream>>>(x, xb, BATCH * SEQ * FEAT);
  transpose_convert<<<dim3(G3 / 32, FEAT / 32), 256, 0, stream>>>(Wk, WkT);
  transpose_convert<<<dim3(G3 / 32, HID  / 32), 256, 0, stream>>>(Wr, WrT);

  proj_mfma<<<dim3(G3 / 128, (BATCH * SEQ) / 128), 256, 0, stream>>>(xb, WkT, bias, xp);

  hipMemsetAsync(hb0, 0, (size_t)BATCH * HID * sizeof(__hip_bfloat16), stream);
  hipMemsetAsync(slots, 0, 16 * 16 * sizeof(int), stream);

  const float* br = bias + G3;
  {
    void* args[] = {(void*)&hb0, (void*)&hb1, (void*)&h32, (void*)&xp,
                    (void*)&WrT, (void*)&br, (void*)&slots};
    hipLaunchCooperativeKernel((void*)gru_persist, dim3(256), dim3(256),
                               args, 0, stream);
  }

  head_kernel<<<256, 64, 0, stream>>>(h32, Wd, bd, out);
}

// Round 12
// 458.856 us; speedup vs baseline: 1.5518x; 1.4086x over previous
//
#include <hip/hip_runtime.h>
#include <hip/hip_bf16.h>
#include <math.h>

constexpr int BATCH = 256;
constexpr int SEQ   = 128;
constexpr int FEAT  = 512;
constexpr int HID   = 512;
constexpr int G3    = 1536;

typedef __bf16 bf16x8 __attribute__((ext_vector_type(8)));
typedef float  f32x4  __attribute__((ext_vector_type(4)));
typedef int    i32x4v __attribute__((ext_vector_type(4)));

// ---------------------------------------------------------------------------
// fp32 -> bf16 convert (vectorized, 8/thread)
// ---------------------------------------------------------------------------
__global__ __launch_bounds__(256) void convert_bf16(
    const float* __restrict__ in, __hip_bfloat16* __restrict__ out, int n)
{
  int i = (blockIdx.x * 256 + threadIdx.x) * 8;
  if (i >= n) return;
  float4 v0 = *(const float4*)&in[i];
  float4 v1 = *(const float4*)&in[i + 4];
  __hip_bfloat16 o[8];
  o[0] = (__hip_bfloat16)v0.x; o[1] = (__hip_bfloat16)v0.y;
  o[2] = (__hip_bfloat16)v0.z; o[3] = (__hip_bfloat16)v0.w;
  o[4] = (__hip_bfloat16)v1.x; o[5] = (__hip_bfloat16)v1.y;
  o[6] = (__hip_bfloat16)v1.z; o[7] = (__hip_bfloat16)v1.w;
  *(int4*)&out[i] = *(int4*)o;
}

// ---------------------------------------------------------------------------
// transpose + convert: in[512][1536] f32 -> outT[1536][512] bf16
// ---------------------------------------------------------------------------
__global__ __launch_bounds__(256) void transpose_convert(
    const float* __restrict__ in, __hip_bfloat16* __restrict__ outT)
{
  __shared__ float tile[32][33];
  const int c0 = blockIdx.x * 32;
  const int r0 = blockIdx.y * 32;
  const int tid = threadIdx.x;
  {
    int row = tid >> 3, c4 = tid & 7;
    float4 v = *(const float4*)&in[(size_t)(r0 + row) * G3 + c0 + c4 * 4];
    tile[row][c4 * 4 + 0] = v.x;
    tile[row][c4 * 4 + 1] = v.y;
    tile[row][c4 * 4 + 2] = v.z;
    tile[row][c4 * 4 + 3] = v.w;
  }
  __syncthreads();
  {
    int rowT = tid >> 3, c4 = tid & 7;
    __hip_bfloat16 o[4];
#pragma unroll
    for (int e = 0; e < 4; ++e)
      o[e] = (__hip_bfloat16)tile[c4 * 4 + e][rowT];
    *(int2*)&outT[(size_t)(c0 + rowT) * FEAT + r0 + c4 * 4] = *(int2*)o;
  }
}

// ---------------------------------------------------------------------------
// proj: 128x128 tile, BK=64, single-buffered global_load_lds staging with
// XOR source/read swizzle (0 bank conflicts, R4-proven). 32 KB LDS +
// __launch_bounds__(256,3) -> 3 blocks/CU for implicit wave-level overlap.
// ---------------------------------------------------------------------------
__global__ __launch_bounds__(256, 3) void proj_mfma(
    const __hip_bfloat16* __restrict__ xb, const __hip_bfloat16* __restrict__ WkT,
    const float* __restrict__ bias, __hip_bfloat16* __restrict__ xp)
{
  __shared__ __align__(16) __hip_bfloat16 As[128 * 64];  // 16 KB, linear
  __shared__ __align__(16) __hip_bfloat16 Bs[128 * 64];

  const int tid = threadIdx.x;
  const int wave = tid >> 6, l = tid & 63;
  const int wm = wave >> 1, wn = wave & 1;
  const int m0 = blockIdx.y * 128;
  const int n0 = blockIdx.x * 128;
  const int lr = l & 15, lh = l >> 4;
  const int swz = lr & 7;

  const int srow = l >> 3;
  const int schk = l & 7;
  const int wrow = wave * 32;

  f32x4 acc[4][4] = {};

  for (int k0 = 0; k0 < FEAT; k0 += 64) {
    __syncthreads();
#pragma unroll
    for (int i = 0; i < 4; ++i) {
      int r = wrow + i * 8 + srow;
      const __hip_bfloat16* srcA = &xb[(size_t)(m0 + r) * FEAT + k0 + ((schk ^ srow) * 8)];
      __builtin_amdgcn_global_load_lds(
          (const __attribute__((address_space(1))) void*)srcA,
          (__attribute__((address_space(3))) void*)&As[(wrow + i * 8) * 64], 16, 0, 0);
    }
#pragma unroll
    for (int i = 0; i < 4; ++i) {
      int r = wrow + i * 8 + srow;
      const __hip_bfloat16* srcB = &WkT[(size_t)(n0 + r) * FEAT + k0 + ((schk ^ srow) * 8)];
      __builtin_amdgcn_global_load_lds(
          (const __attribute__((address_space(1))) void*)srcB,
          (__attribute__((address_space(3))) void*)&Bs[(wrow + i * 8) * 64], 16, 0, 0);
    }
    __syncthreads();

#pragma unroll
    for (int ks = 0; ks < 2; ++ks) {
      bf16x8 a[4], b[4];
#pragma unroll
      for (int i = 0; i < 4; ++i) {
        int row = wm * 64 + i * 16 + lr;
        a[i] = *(const bf16x8*)&As[row * 64 + (((ks * 4 + lh) ^ swz) * 8)];
      }
#pragma unroll
      for (int j = 0; j < 4; ++j) {
        int row = wn * 64 + j * 16 + lr;
        b[j] = *(const bf16x8*)&Bs[row * 64 + (((ks * 4 + lh) ^ swz) * 8)];
      }
#pragma unroll
      for (int i = 0; i < 4; ++i)
#pragma unroll
        for (int j = 0; j < 4; ++j)
          acc[i][j] = __builtin_amdgcn_mfma_f32_16x16x32_bf16(a[i], b[j], acc[i][j], 0, 0, 0);
    }
  }

  float bv[4];
#pragma unroll
  for (int j = 0; j < 4; ++j)
    bv[j] = bias[n0 + wn * 64 + j * 16 + lr];
#pragma unroll
  for (int i = 0; i < 4; ++i)
#pragma unroll
    for (int j = 0; j < 4; ++j) {
      int n = n0 + wn * 64 + j * 16 + lr;
#pragma unroll
      for (int r = 0; r < 4; ++r) {
        int m = m0 + wm * 64 + i * 16 + lh * 4 + r;
        xp[(size_t)m * G3 + n] = (__hip_bfloat16)(acc[i][j][r] + bv[j]);
      }
    }
}

// ---------------------------------------------------------------------------
// Persistent GRU recurrence, v8 = EXACT R7 protocol (proven 2.64 us/step):
//   batched coherent h loads, register-pinned W, pre-flag __syncthreads,
//   leader-only flag store + sleep-throttled leader poll, post barrier.
// ONE change vs R7: xp(t+1) prefetch moved from BEFORE the pre-flag barrier
// (where it polluted the vmcnt drain) to BETWEEN the barriers (hides under
// the leader's poll).
// Grid 256: blockIdx.x = jt*16 + bt.
// ---------------------------------------------------------------------------
__global__ __launch_bounds__(256, 1) void gru_persist(
    __hip_bfloat16* __restrict__ hbA, __hip_bfloat16* __restrict__ hbB,
    float* __restrict__ h32,
    const __hip_bfloat16* __restrict__ xp,
    const __hip_bfloat16* __restrict__ WrT,
    const float* __restrict__ br,
    int* slots)                               // [16][16] ints
{
  __shared__ float red[2 * 16 * 100];

  const int tid = threadIdx.x;
  const int bt = blockIdx.x & 15;
  const int jt = blockIdx.x >> 4;
  const int wave = tid >> 6, l = tid & 63;
  const int kh = wave & 1, ch = wave >> 1;
  const int lr = l & 15, lh = l >> 4;

  // ---- one-time: W fragments -> registers (24 x 16B per lane), pinned ----
  bf16x8 wfrag[8][3];
#pragma unroll
  for (int f = 0; f < 3; ++f) {
    int r = ch * 48 + f * 16 + lr;
    int n = (r >> 5) * HID + jt * 32 + (r & 31);
    const __hip_bfloat16* wp = &WrT[(size_t)n * HID + kh * 256 + lh * 8];
#pragma unroll
    for (int ks = 0; ks < 8; ++ks)
      wfrag[ks][f] = *(const bf16x8*)&wp[ks * 32];
  }
  asm volatile(""
      : "+v"(wfrag[0][0]), "+v"(wfrag[0][1]), "+v"(wfrag[0][2]),
        "+v"(wfrag[1][0]), "+v"(wfrag[1][1]), "+v"(wfrag[1][2]),
        "+v"(wfrag[2][0]), "+v"(wfrag[2][1]), "+v"(wfrag[2][2]),
        "+v"(wfrag[3][0]), "+v"(wfrag[3][1]), "+v"(wfrag[3][2]),
        "+v"(wfrag[4][0]), "+v"(wfrag[4][1]), "+v"(wfrag[4][2]),
        "+v"(wfrag[5][0]), "+v"(wfrag[5][1]), "+v"(wfrag[5][2]),
        "+v"(wfrag[6][0]), "+v"(wfrag[6][1]), "+v"(wfrag[6][2]),
        "+v"(wfrag[7][0]), "+v"(wfrag[7][1]), "+v"(wfrag[7][2]));

  // ---- per-thread epilogue ownership ----
  const int m = tid >> 4, q4 = tid & 15;
  const int b = bt * 16 + m;
  const int jl0 = q4 * 2;
  const int jg0 = jt * 32 + jl0;
  float brz[2], brr[2], brh[2], hreg[2];
#pragma unroll
  for (int p = 0; p < 2; ++p) {
    brz[p] = br[jg0 + p];
    brr[p] = br[HID + jg0 + p];
    brh[p] = br[2 * HID + jg0 + p];
    hreg[p] = 0.f;
  }

  // preload xp for t=0 (u32 = 2 consecutive bf16)
  unsigned int uz, ur_, uh_;
  {
    const __hip_bfloat16* xq = &xp[((size_t)b * SEQ + 0) * G3 + jg0];
    uz  = *(const unsigned int*)&xq[0];
    ur_ = *(const unsigned int*)&xq[HID];
    uh_ = *(const unsigned int*)&xq[2 * HID];
  }

  // per-lane h-fragment base (bytes)
  const char* baseA = (const char*)hbA + ((size_t)(bt * 16 + lr) * HID + kh * 256 + lh * 8) * 2;
  const char* baseB = (const char*)hbB + ((size_t)(bt * 16 + lr) * HID + kh * 256 + lh * 8) * 2;

  for (int t = 0; t < SEQ; ++t) {
    const char* hp = (t & 1) ? baseB : baseA;
    __hip_bfloat16* nxt = (t & 1) ? hbA : hbB;

    // ---- h fragments: 8 batched coherent 16B loads, ONE waitcnt ----
    i32x4v r0, r1, r2, r3, r4, r5, r6, r7;
    asm volatile(
        "global_load_dwordx4 %0, %8, off sc0 sc1\n\t"
        "global_load_dwordx4 %1, %8, off offset:64 sc0 sc1\n\t"
        "global_load_dwordx4 %2, %8, off offset:128 sc0 sc1\n\t"
        "global_load_dwordx4 %3, %8, off offset:192 sc0 sc1\n\t"
        "global_load_dwordx4 %4, %8, off offset:256 sc0 sc1\n\t"
        "global_load_dwordx4 %5, %8, off offset:320 sc0 sc1\n\t"
        "global_load_dwordx4 %6, %8, off offset:384 sc0 sc1\n\t"
        "global_load_dwordx4 %7, %8, off offset:448 sc0 sc1\n\t"
        "s_waitcnt vmcnt(0)"
        : "=&v"(r0), "=&v"(r1), "=&v"(r2), "=&v"(r3),
          "=&v"(r4), "=&v"(r5), "=&v"(r6), "=&v"(r7)
        : "v"(hp)
        : "memory");
    union { i32x4v q; bf16x8 v; } u0, u1, u2, u3, u4, u5, u6, u7;
    u0.q = r0; u1.q = r1; u2.q = r2; u3.q = r3;
    u4.q = r4; u5.q = r5; u6.q = r6; u7.q = r7;
    bf16x8 afrag[8] = {u0.v, u1.v, u2.v, u3.v, u4.v, u5.v, u6.v, u7.v};

    // ---- MFMA: pure register operands ----
    f32x4 acc[3] = {};
#pragma unroll
    for (int ks = 0; ks < 8; ++ks)
#pragma unroll
      for (int f = 0; f < 3; ++f)
        acc[f] = __builtin_amdgcn_mfma_f32_16x16x32_bf16(afrag[ks], wfrag[ks][f], acc[f], 0, 0, 0);

#pragma unroll
    for (int f = 0; f < 3; ++f)
#pragma unroll
      for (int i = 0; i < 4; ++i)
        red[kh * 1600 + (lh * 4 + i) * 100 + ch * 48 + f * 16 + lr] = acc[f][i];
    __syncthreads();

    // ---- epilogue ----
    {
      float xzv[2], xrv[2], xhv[2];
      xzv[0] = (float)((__hip_bfloat16*)&uz)[0];  xzv[1] = (float)((__hip_bfloat16*)&uz)[1];
      xrv[0] = (float)((__hip_bfloat16*)&ur_)[0]; xrv[1] = (float)((__hip_bfloat16*)&ur_)[1];
      xhv[0] = (float)((__hip_bfloat16*)&uh_)[0]; xhv[1] = (float)((__hip_bfloat16*)&uh_)[1];
      float hn[2];
#pragma unroll
      for (int p = 0; p < 2; ++p) {
        int jl = jl0 + p;
        float rz = red[m * 100 + jl]      + red[1600 + m * 100 + jl];
        float rr = red[m * 100 + 32 + jl] + red[1600 + m * 100 + 32 + jl];
        float rh = red[m * 100 + 64 + jl] + red[1600 + m * 100 + 64 + jl];
        rz += brz[p]; rr += brr[p]; rh += brh[p];
        float z  = 1.f / (1.f + __expf(-(xzv[p] + rz)));
        float rg = 1.f / (1.f + __expf(-(xrv[p] + rr)));
        float hh = fmaxf(xhv[p] + rg * rh, 0.f);
        hn[p] = z * hreg[p] + (1.f - z) * hh;
        hreg[p] = hn[p];
      }
      if (t < SEQ - 1) {
        __hip_bfloat16 h0 = (__hip_bfloat16)hn[0], h1 = (__hip_bfloat16)hn[1];
        unsigned int pk = (unsigned int)*(unsigned short*)&h0 |
                          ((unsigned int)*(unsigned short*)&h1 << 16);
        __hip_atomic_store(
            (unsigned int*)&nxt[(size_t)b * HID + jg0], pk,
            __ATOMIC_RELAXED, __HIP_MEMORY_SCOPE_AGENT);
      }
    }

    // ---- group barrier: R7 protocol; xp prefetch now BETWEEN barriers ----
    if (t < SEQ - 1) {
      __syncthreads();   // drains h stores ONLY (xp prefetch moved below)

      // xp(t+1) prefetch — issued after the drain, completes under the poll
      {
        const __hip_bfloat16* xq = &xp[((size_t)b * SEQ + t + 1) * G3 + jg0];
        uz  = *(const unsigned int*)&xq[0];
        ur_ = *(const unsigned int*)&xq[HID];
        uh_ = *(const unsigned int*)&xq[2 * HID];
      }

      if (tid == 0) {
        __hip_atomic_store(&slots[bt * 16 + jt], t + 1,
                           __ATOMIC_RELAXED, __HIP_MEMORY_SCOPE_AGENT);
        const char* fl = (const char*)&slots[bt * 16];
        for (;;) {
          i32x4v p0, p1, p2, p3;
          asm volatile(
              "global_load_dwordx4 %0, %4, off sc0 sc1\n\t"
              "global_load_dwordx4 %1, %4, off offset:16 sc0 sc1\n\t"
              "global_load_dwordx4 %2, %4, off offset:32 sc0 sc1\n\t"
              "global_load_dwordx4 %3, %4, off offset:48 sc0 sc1\n\t"
              "s_waitcnt vmcnt(0)"
              : "=&v"(p0), "=&v"(p1), "=&v"(p2), "=&v"(p3)
              : "v"(fl)
              : "memory");
          int t1 = t + 1;
          int ok = (p0[0] >= t1) & (p0[1] >= t1) & (p0[2] >= t1) & (p0[3] >= t1) &
                   (p1[0] >= t1) & (p1[1] >= t1) & (p1[2] >= t1) & (p1[3] >= t1) &
                   (p2[0] >= t1) & (p2[1] >= t1) & (p2[2] >= t1) & (p2[3] >= t1) &
                   (p3[0] >= t1) & (p3[1] >= t1) & (p3[2] >= t1) & (p3[3] >= t1);
          if (ok) break;
          __builtin_amdgcn_s_sleep(1);
        }
      }
      __syncthreads();
    }
  }

  // final fp32 h
#pragma unroll
  for (int p = 0; p < 2; ++p)
    h32[(size_t)b * HID + jg0 + p] = hreg[p];
}

// ---------------------------------------------------------------------------
// head: out[b] = h32[b][:] . Wd + bd
// ---------------------------------------------------------------------------
__global__ __launch_bounds__(64) void head_kernel(
    const float* __restrict__ h32, const float* __restrict__ Wd,
    const float* __restrict__ bd, float* __restrict__ out)
{
  int b = blockIdx.x, l = threadIdx.x;
  const float* hr = &h32[(size_t)b * HID];
  float s = 0.f;
#pragma unroll
  for (int i = 0; i < 8; ++i)
    s += hr[l + i * 64] * Wd[l + i * 64];
#pragma unroll
  for (int off = 32; off; off >>= 1) s += __shfl_down(s, off);
  if (l == 0) out[b] = s + bd[0];
}

// ---------------------------------------------------------------------------
extern "C" void kernel_launch(void* const* d_in, const int* in_sizes, int n_in,
                              void* d_out, int out_size, void* d_ws, size_t ws_size,
                              hipStream_t stream) {
  const float* x    = (const float*)d_in[0];
  const float* Wk   = (const float*)d_in[1];
  const float* Wr   = (const float*)d_in[2];
  const float* bias = (const float*)d_in[3];
  const float* Wd   = (const float*)d_in[4];
  const float* bd   = (const float*)d_in[5];
  float* out = (float*)d_out;

  char* ws = (char*)d_ws;
  size_t off = 0;
  __hip_bfloat16* xp  = (__hip_bfloat16*)(ws + off); off += (size_t)BATCH * SEQ * G3 * 2;
  __hip_bfloat16* xb  = (__hip_bfloat16*)(ws + off); off += (size_t)BATCH * SEQ * FEAT * 2;
  __hip_bfloat16* WkT = (__hip_bfloat16*)(ws + off); off += (size_t)G3 * FEAT * 2;
  __hip_bfloat16* WrT = (__hip_bfloat16*)(ws + off); off += (size_t)G3 * HID * 2;
  float*          h32 = (float*)(ws + off);          off += (size_t)BATCH * HID * 4;
  __hip_bfloat16* hb0 = (__hip_bfloat16*)(ws + off); off += (size_t)BATCH * HID * 2;
  __hip_bfloat16* hb1 = (__hip_bfloat16*)(ws + off); off += (size_t)BATCH * HID * 2;
  int*            slots = (int*)(ws + off);          off += 16 * 16 * sizeof(int);

  convert_bf16<<<(BATCH * SEQ * FEAT) / (256 * 8), 256, 0, stream>>>(x, xb, BATCH * SEQ * FEAT);
  transpose_convert<<<dim3(G3 / 32, FEAT / 32), 256, 0, stream>>>(Wk, WkT);
  transpose_convert<<<dim3(G3 / 32, HID  / 32), 256, 0, stream>>>(Wr, WrT);

  proj_mfma<<<dim3(G3 / 128, (BATCH * SEQ) / 128), 256, 0, stream>>>(xb, WkT, bias, xp);

  hipMemsetAsync(hb0, 0, (size_t)BATCH * HID * sizeof(__hip_bfloat16), stream);
  hipMemsetAsync(slots, 0, 16 * 16 * sizeof(int), stream);

  const float* br = bias + G3;
  {
    void* args[] = {(void*)&hb0, (void*)&hb1, (void*)&h32, (void*)&xp,
                    (void*)&WrT, (void*)&br, (void*)&slots};
    hipLaunchCooperativeKernel((void*)gru_persist, dim3(256), dim3(256),
                               args, 0, stream);
  }

  head_kernel<<<256, 64, 0, stream>>>(h32, Wd, bd, out);
}